// Round 1
// baseline (4354.035 us; speedup 1.0000x reference)
//
#include <hip/hip_runtime.h>
#include <hip/hip_bf16.h>

// Problem dims
#define BSZ 32
#define SSZ 512
#define ISZ 512
#define HSZ 512
#define PW  32          // workgroups per direction
// ws layout (bytes)
#define XB_OFF   0ull                       // [S][64 kc][32 b][8] ushort (bf16 bits) = 16 MB
#define HEX_OFF  (16ull << 20)              // [2 dir][2 buf][64 kc][32 b][8] ushort = 128 KB
#define CTR_OFF  (HEX_OFF + (128ull << 10)) // [2*512] counters, 16 dwords apart = 64 KB

typedef __attribute__((ext_vector_type(8)))  short short8;
typedef __attribute__((ext_vector_type(4)))  float f32x4;
typedef __attribute__((ext_vector_type(4)))  unsigned short us4;

__device__ __forceinline__ unsigned short f2bf(float f) {
    union { float f; unsigned u; } v; v.f = f;
    unsigned r = v.u + 0x7fffu + ((v.u >> 16) & 1u);   // RNE
    return (unsigned short)(r >> 16);
}

__device__ __forceinline__ float sigf(float x) { return 1.0f / (1.0f + __expf(-x)); }
__device__ __forceinline__ float tanhfast(float x) {
    float a = fabsf(x);
    float e = __expf(-2.0f * a);
    float t = (1.0f - e) / (1.0f + e);
    return x < 0.0f ? -t : t;
}

// X [B][S][I] fp32 -> Xb [t][kc][b][8] bf16-bits (MFMA A-fragment friendly layout)
__global__ void k_xpose(const float* __restrict__ X, unsigned short* __restrict__ Xb) {
    int idx = blockIdx.x * 256 + threadIdx.x;     // 2^21 threads total
    int i4 = idx & 127;                           // float4 index along I
    int t  = (idx >> 7) & 511;
    int b  = idx >> 16;
    float4 v = reinterpret_cast<const float4*>(X)[idx];
    us4 o = { f2bf(v.x), f2bf(v.y), f2bf(v.z), f2bf(v.w) };
    // elements i = i4*4 .. +4 ; kc = i>>3 = i4>>1 ; e = (i4&1)*4
    *reinterpret_cast<us4*>(Xb + (size_t)t * 16384 + (size_t)(i4 >> 1) * 256 + b * 8 + (i4 & 1) * 4) = o;
}

__launch_bounds__(256, 1)
__global__ void k_bilstm(const float* __restrict__ Wih_f, const float* __restrict__ Whh_f,
                         const float* __restrict__ bih_f, const float* __restrict__ bhh_f,
                         const float* __restrict__ Wih_b, const float* __restrict__ Whh_b,
                         const float* __restrict__ bih_b, const float* __restrict__ bhh_b,
                         const unsigned short* __restrict__ Xb,
                         unsigned short* h_ex, unsigned* ctr, float* __restrict__ out)
{
    const int tid = threadIdx.x;
    const int dir = blockIdx.x & 1;     // 0 = fwd, 1 = bwd
    const int p   = blockIdx.x >> 1;    // 0..31 : owns h-cols [16p, 16p+16)
    const int wv  = tid >> 6;
    const int ln  = tid & 63;
    const int kh  = wv >> 1;            // 0: x-projection, 1: h-recurrence
    const int nt  = wv & 1;             // gate-pair tile (0: i,f ; 1: g,o)
    const int q   = ln >> 4;            // quad within wave
    const int m15 = ln & 15;

    const float* Wsel = kh ? (dir ? Whh_b : Whh_f) : (dir ? Wih_b : Wih_f);
    const float* bi   = dir ? bih_b : bih_f;
    const float* bh   = dir ? bhh_b : bhh_f;

    __shared__ float gates[2][32][66];
    __shared__ float cst[32][16];
    __shared__ float bias[64];

    // ---- load B fragments (weights) into registers, kept for all 512 steps ----
    // B[k][n] = W[gatecol(n)][k]; lane: n = m15, k = q*8 + j + ks*32 ; two 16-col subtiles (nn)
    short8 breg[16][2];
    {
        const float* wr0 = Wsel + (size_t)((nt * 2 + 0) * 512 + p * 16 + m15) * 512 + q * 8;
        const float* wr1 = Wsel + (size_t)((nt * 2 + 1) * 512 + p * 16 + m15) * 512 + q * 8;
#pragma unroll
        for (int ks = 0; ks < 16; ++ks) {
            short8 b0, b1;
#pragma unroll
            for (int j = 0; j < 8; ++j) {
                b0[j] = (short)f2bf(wr0[ks * 32 + j]);
                b1[j] = (short)f2bf(wr1[ks * 32 + j]);
            }
            breg[ks][0] = b0; breg[ks][1] = b1;
        }
    }

    // bias (bih+bhh) for this WG's 64 gate-cols; c-state = 0
    if (tid < 64) {
        int c = tid;
        int gr = (c >> 4) * 512 + p * 16 + (c & 15);
        bias[c] = bi[gr] + bh[gr];
    }
    for (int i = tid; i < 512; i += 256) ((float*)cst)[i] = 0.0f;
    __syncthreads();

    unsigned* myctr = ctr + (size_t)dir * 512 * 16;
    const unsigned short* hex_rd0 = h_ex + (size_t)dir * 2 * 16384;
    unsigned short*       hex_wr0 = h_ex + (size_t)dir * 2 * 16384;

    for (int s = 0; s < 512; ++s) {
        const int t = dir ? (511 - s) : s;
        // A source: x-waves read Xb[t]; h-waves read h(s-1) (buffer (s+1)&1; zeroed for s=0)
        const unsigned short* abase = (kh == 0) ? (Xb + (size_t)t * 16384)
                                                : (hex_rd0 + (size_t)((s + 1) & 1) * 16384);

        // ---- wait for step s-1 to be fully published ----
        if (s > 0) {
            if (tid == 0) {
                unsigned idx = (unsigned)(s - 1) * 16;
                while (__hip_atomic_load(myctr + idx, __ATOMIC_ACQUIRE, __HIP_MEMORY_SCOPE_AGENT) < PW)
                    __builtin_amdgcn_s_sleep(2);
            }
            __syncthreads();
        }

        // ---- GEMM: [32 x 512] @ [512 x 32cols] for this wave's K-half ----
        f32x4 acc00 = {0.f,0.f,0.f,0.f}, acc01 = {0.f,0.f,0.f,0.f};
        f32x4 acc10 = {0.f,0.f,0.f,0.f}, acc11 = {0.f,0.f,0.f,0.f};
#pragma unroll
        for (int ks = 0; ks < 16; ++ks) {
            const unsigned short* ap = abase + (size_t)(ks * 4 + q) * 256 + m15 * 8;
            short8 a0 = *reinterpret_cast<const short8*>(ap);        // batches 0..15
            short8 a1 = *reinterpret_cast<const short8*>(ap + 128);  // batches 16..31
            acc00 = __builtin_amdgcn_mfma_f32_16x16x32_bf16(a0, breg[ks][0], acc00, 0, 0, 0);
            acc01 = __builtin_amdgcn_mfma_f32_16x16x32_bf16(a0, breg[ks][1], acc01, 0, 0, 0);
            acc10 = __builtin_amdgcn_mfma_f32_16x16x32_bf16(a1, breg[ks][0], acc10, 0, 0, 0);
            acc11 = __builtin_amdgcn_mfma_f32_16x16x32_bf16(a1, breg[ks][1], acc11, 0, 0, 0);
        }

        // ---- dump partial gates to LDS (C/D layout: col = ln&15, row = q*4 + r) ----
        {
            int rb = q * 4;
            int cb = nt * 32 + m15;
#pragma unroll
            for (int r = 0; r < 4; ++r) {
                gates[kh][rb + r][cb]           = acc00[r];
                gates[kh][rb + r][cb + 16]      = acc01[r];
                gates[kh][16 + rb + r][cb]      = acc10[r];
                gates[kh][16 + rb + r][cb + 16] = acc11[r];
            }
        }
        __syncthreads();

        // ---- gate math: each thread handles (b, j), (b, j+1) ----
        {
            int b  = tid >> 3;
            int j0 = (tid & 7) * 2;
#pragma unroll
            for (int u = 0; u < 2; ++u) {
                int j = j0 + u;
                float ig = gates[0][b][j]      + gates[1][b][j]      + bias[j];
                float fg = gates[0][b][16 + j] + gates[1][b][16 + j] + bias[16 + j];
                float gg = gates[0][b][32 + j] + gates[1][b][32 + j] + bias[32 + j];
                float og = gates[0][b][48 + j] + gates[1][b][48 + j] + bias[48 + j];
                float cn = sigf(fg) * cst[b][j] + sigf(ig) * tanhfast(gg);
                cst[b][j] = cn;
                float hv = sigf(og) * tanhfast(cn);
                int hc = p * 16 + j;
                out[(size_t)b * (512 * 1024) + (size_t)t * 1024 + dir * 512 + hc] = hv;
                hex_wr0[(size_t)(s & 1) * 16384 + (size_t)(hc >> 3) * 256 + b * 8 + (hc & 7)] = f2bf(hv);
                if (s == 511) {
                    out[16777216 + dir * 16384 + b * 512 + hc] = hv;           // stacked_h
                    out[16777216 + 32768 + dir * 16384 + b * 512 + hc] = cn;   // stacked_c
                }
            }
        }
        __syncthreads();   // all h_ex writes done before publish

        // ---- publish step s ----
        if (tid == 0) {
            __threadfence();
            __hip_atomic_fetch_add(myctr + (size_t)s * 16, 1u, __ATOMIC_RELEASE, __HIP_MEMORY_SCOPE_AGENT);
        }
    }
}

extern "C" void kernel_launch(void* const* d_in, const int* in_sizes, int n_in,
                              void* d_out, int out_size, void* d_ws, size_t ws_size,
                              hipStream_t stream) {
    const float* X     = (const float*)d_in[0];
    const float* Wih_f = (const float*)d_in[1];
    const float* Whh_f = (const float*)d_in[2];
    const float* bih_f = (const float*)d_in[3];
    const float* bhh_f = (const float*)d_in[4];
    const float* Wih_b = (const float*)d_in[5];
    const float* Whh_b = (const float*)d_in[6];
    const float* bih_b = (const float*)d_in[7];
    const float* bhh_b = (const float*)d_in[8];
    float* out = (float*)d_out;

    unsigned short* Xb   = (unsigned short*)((char*)d_ws + XB_OFF);
    unsigned short* h_ex = (unsigned short*)((char*)d_ws + HEX_OFF);
    unsigned*       ctr  = (unsigned*)((char*)d_ws + CTR_OFF);

    // zero h_ex (h_{-1}=0) + barrier counters
    hipMemsetAsync((char*)d_ws + HEX_OFF, 0, (128ull + 64ull) << 10, stream);
    k_xpose<<<8192, 256, 0, stream>>>(X, Xb);
    k_bilstm<<<64, 256, 0, stream>>>(Wih_f, Whh_f, bih_f, bhh_f,
                                     Wih_b, Whh_b, bih_b, bhh_b,
                                     Xb, h_ex, ctr, out);
}

// Round 2
// 4263.714 us; speedup vs baseline: 1.0212x; 1.0212x over previous
//
#include <hip/hip_runtime.h>
#include <hip/hip_bf16.h>

// Problem dims
#define BSZ 32
#define SSZ 512
#define ISZ 512
#define HSZ 512
#define PW  32          // workgroups per direction
#define FLAG_TARGET 128u // 32 WGs * 4 waves per direction publish per step
// ws layout (bytes)
#define XB_OFF   0ull                       // [S][64 kc][32 b][8] ushort (bf16 bits) = 16 MB
#define HEX_OFF  (16ull << 20)              // [2 dir][2 buf][64 kc][32 b][8] ushort = 128 KB
#define CTR_OFF  (HEX_OFF + (128ull << 10)) // [2*512] counters, 16 dwords apart = 64 KB

typedef __attribute__((ext_vector_type(8)))  short short8;
typedef __attribute__((ext_vector_type(4)))  float f32x4;
typedef __attribute__((ext_vector_type(4)))  unsigned short us4;

__device__ __forceinline__ unsigned short f2bf(float f) {
    union { float f; unsigned u; } v; v.f = f;
    unsigned r = v.u + 0x7fffu + ((v.u >> 16) & 1u);   // RNE
    return (unsigned short)(r >> 16);
}

__device__ __forceinline__ float sigf(float x) { return 1.0f / (1.0f + __expf(-x)); }
__device__ __forceinline__ float tanhfast(float x) {
    float a = fabsf(x);
    float e = __expf(-2.0f * a);
    float t = (1.0f - e) / (1.0f + e);
    return x < 0.0f ? -t : t;
}

// X [B][S][I] fp32 -> Xb [t][kc][b][8] bf16-bits (MFMA A-fragment friendly layout)
__global__ void k_xpose(const float* __restrict__ X, unsigned short* __restrict__ Xb) {
    int idx = blockIdx.x * 256 + threadIdx.x;     // 2^21 threads total
    int i4 = idx & 127;                           // float4 index along I
    int t  = (idx >> 7) & 511;
    int b  = idx >> 16;
    float4 v = reinterpret_cast<const float4*>(X)[idx];
    us4 o = { f2bf(v.x), f2bf(v.y), f2bf(v.z), f2bf(v.w) };
    *reinterpret_cast<us4*>(Xb + (size_t)t * 16384 + (size_t)(i4 >> 1) * 256 + b * 8 + (i4 & 1) * 4) = o;
}

__launch_bounds__(256, 1)
__global__ void k_bilstm(const float* __restrict__ Wih_f, const float* __restrict__ Whh_f,
                         const float* __restrict__ bih_f, const float* __restrict__ bhh_f,
                         const float* __restrict__ Wih_b, const float* __restrict__ Whh_b,
                         const float* __restrict__ bih_b, const float* __restrict__ bhh_b,
                         const unsigned short* __restrict__ Xb,
                         unsigned short* h_ex, unsigned* ctr, float* __restrict__ out)
{
    const int tid = threadIdx.x;
    const int dir = blockIdx.x & 1;     // 0 = fwd, 1 = bwd
    const int p   = blockIdx.x >> 1;    // 0..31 : owns h-cols [16p, 16p+16)
    const int wv  = tid >> 6;
    const int ln  = tid & 63;
    const int kh  = wv >> 1;            // 0: x-projection, 1: h-recurrence
    const int nt  = wv & 1;             // gate-pair tile (0: i,f ; 1: g,o)
    const int q   = ln >> 4;            // quad within wave
    const int m15 = ln & 15;

    const float* Wsel = kh ? (dir ? Whh_b : Whh_f) : (dir ? Wih_b : Wih_f);
    const float* bi   = dir ? bih_b : bih_f;
    const float* bh   = dir ? bhh_b : bhh_f;

    __shared__ float gates[2][32][66];
    __shared__ float cst[32][16];
    __shared__ float bias[64];

    // ---- load B fragments (weights) into registers, kept for all 512 steps ----
    short8 breg[16][2];
    {
        const float* wr0 = Wsel + (size_t)((nt * 2 + 0) * 512 + p * 16 + m15) * 512 + q * 8;
        const float* wr1 = Wsel + (size_t)((nt * 2 + 1) * 512 + p * 16 + m15) * 512 + q * 8;
#pragma unroll
        for (int ks = 0; ks < 16; ++ks) {
            short8 b0, b1;
#pragma unroll
            for (int j = 0; j < 8; ++j) {
                b0[j] = (short)f2bf(wr0[ks * 32 + j]);
                b1[j] = (short)f2bf(wr1[ks * 32 + j]);
            }
            breg[ks][0] = b0; breg[ks][1] = b1;
        }
    }

    if (tid < 64) {
        int c = tid;
        int gr = (c >> 4) * 512 + p * 16 + (c & 15);
        bias[c] = bi[gr] + bh[gr];
    }
    for (int i = tid; i < 512; i += 256) ((float*)cst)[i] = 0.0f;
    __syncthreads();

    unsigned* myctr = ctr + (size_t)dir * 512 * 16;
    unsigned short* hexd = h_ex + (size_t)dir * 2 * 16384;

    for (int s = 0; s < 512; ++s) {
        const int t = dir ? (511 - s) : s;

        // ---- GEMM: [32 x 512] @ [512 x 32cols] for this wave's K-half ----
        f32x4 acc00 = {0.f,0.f,0.f,0.f}, acc01 = {0.f,0.f,0.f,0.f};
        f32x4 acc10 = {0.f,0.f,0.f,0.f}, acc11 = {0.f,0.f,0.f,0.f};

        if (kh == 0) {
            // x-projection: no waiting ever; plain (L2-cacheable) loads
            const unsigned short* abase = Xb + (size_t)t * 16384;
#pragma unroll
            for (int ks = 0; ks < 16; ++ks) {
                const unsigned short* ap = abase + (size_t)(ks * 4 + q) * 256 + m15 * 8;
                short8 a0 = *reinterpret_cast<const short8*>(ap);
                short8 a1 = *reinterpret_cast<const short8*>(ap + 128);
                acc00 = __builtin_amdgcn_mfma_f32_16x16x32_bf16(a0, breg[ks][0], acc00, 0, 0, 0);
                acc01 = __builtin_amdgcn_mfma_f32_16x16x32_bf16(a0, breg[ks][1], acc01, 0, 0, 0);
                acc10 = __builtin_amdgcn_mfma_f32_16x16x32_bf16(a1, breg[ks][0], acc10, 0, 0, 0);
                acc11 = __builtin_amdgcn_mfma_f32_16x16x32_bf16(a1, breg[ks][1], acc11, 0, 0, 0);
            }
        } else {
            // h-recurrence: wait for step s-1 (relaxed agent poll -> sc1, no cache maintenance)
            if (s > 0) {
                const unsigned* flag = myctr + (size_t)(s - 1) * 16;
                while (__hip_atomic_load(flag, __ATOMIC_RELAXED, __HIP_MEMORY_SCOPE_AGENT) < FLAG_TARGET) {}
                asm volatile("" ::: "memory");
            }
            const unsigned* abase = reinterpret_cast<const unsigned*>(hexd + (size_t)((s + 1) & 1) * 16384);
#pragma unroll
            for (int ks = 0; ks < 16; ++ks) {
                const unsigned* ap = abase + ((ks * 4 + q) * 256 + m15 * 8) / 2;
                union { short8 s8; unsigned u[4]; } ua0, ua1;
#pragma unroll
                for (int w = 0; w < 4; ++w) {
                    ua0.u[w] = __hip_atomic_load(ap + w,      __ATOMIC_RELAXED, __HIP_MEMORY_SCOPE_AGENT);
                    ua1.u[w] = __hip_atomic_load(ap + 64 + w, __ATOMIC_RELAXED, __HIP_MEMORY_SCOPE_AGENT);
                }
                acc00 = __builtin_amdgcn_mfma_f32_16x16x32_bf16(ua0.s8, breg[ks][0], acc00, 0, 0, 0);
                acc01 = __builtin_amdgcn_mfma_f32_16x16x32_bf16(ua0.s8, breg[ks][1], acc01, 0, 0, 0);
                acc10 = __builtin_amdgcn_mfma_f32_16x16x32_bf16(ua1.s8, breg[ks][0], acc10, 0, 0, 0);
                acc11 = __builtin_amdgcn_mfma_f32_16x16x32_bf16(ua1.s8, breg[ks][1], acc11, 0, 0, 0);
            }
        }

        // ---- dump partial gates to LDS (C/D layout: col = ln&15, row = q*4 + r) ----
        {
            int rb = q * 4;
            int cb = nt * 32 + m15;
#pragma unroll
            for (int r = 0; r < 4; ++r) {
                gates[kh][rb + r][cb]           = acc00[r];
                gates[kh][rb + r][cb + 16]      = acc01[r];
                gates[kh][16 + rb + r][cb]      = acc10[r];
                gates[kh][16 + rb + r][cb + 16] = acc11[r];
            }
        }
        __syncthreads();   // sync#1: both dumps visible

        // ---- gate math: each thread handles (b, j0) and (b, j0+1) ----
        {
            int b  = tid >> 3;
            int j0 = (tid & 7) * 2;
            float hv01[2], cn01[2];
#pragma unroll
            for (int u = 0; u < 2; ++u) {
                int j = j0 + u;
                float ig = gates[0][b][j]      + gates[1][b][j]      + bias[j];
                float fg = gates[0][b][16 + j] + gates[1][b][16 + j] + bias[16 + j];
                float gg = gates[0][b][32 + j] + gates[1][b][32 + j] + bias[32 + j];
                float og = gates[0][b][48 + j] + gates[1][b][48 + j] + bias[48 + j];
                float cn = sigf(fg) * cst[b][j] + sigf(ig) * tanhfast(gg);
                cst[b][j] = cn;
                float hv = sigf(og) * tanhfast(cn);
                hv01[u] = hv; cn01[u] = cn;
                int hc = p * 16 + j;
                out[(size_t)b * (512 * 1024) + (size_t)t * 1024 + dir * 512 + hc] = hv;
                if (s == 511) {
                    out[16777216 + dir * 16384 + b * 512 + hc] = hv;           // stacked_h
                    out[16777216 + 32768 + dir * 16384 + b * 512 + hc] = cn;   // stacked_c
                }
            }
            // packed 2xbf16 write-through (sc1) store of h for the next step
            int hc0 = p * 16 + j0;
            unsigned pk = (unsigned)f2bf(hv01[0]) | ((unsigned)f2bf(hv01[1]) << 16);
            unsigned* dst = reinterpret_cast<unsigned*>(
                hexd + (size_t)(s & 1) * 16384 + (size_t)(hc0 >> 3) * 256 + b * 8 + (hc0 & 7));
            __hip_atomic_store(dst, pk, __ATOMIC_RELAXED, __HIP_MEMORY_SCOPE_AGENT);
        }

        // ---- per-wave publish: drain this wave's stores, then bump the flag ----
        asm volatile("s_waitcnt vmcnt(0)" ::: "memory");
        if (ln == 0) {
            __hip_atomic_fetch_add(myctr + (size_t)s * 16, 1u, __ATOMIC_RELAXED, __HIP_MEMORY_SCOPE_AGENT);
        }

        __syncthreads();   // sync#2: gates/cst safe to overwrite next step
    }
}

extern "C" void kernel_launch(void* const* d_in, const int* in_sizes, int n_in,
                              void* d_out, int out_size, void* d_ws, size_t ws_size,
                              hipStream_t stream) {
    const float* X     = (const float*)d_in[0];
    const float* Wih_f = (const float*)d_in[1];
    const float* Whh_f = (const float*)d_in[2];
    const float* bih_f = (const float*)d_in[3];
    const float* bhh_f = (const float*)d_in[4];
    const float* Wih_b = (const float*)d_in[5];
    const float* Whh_b = (const float*)d_in[6];
    const float* bih_b = (const float*)d_in[7];
    const float* bhh_b = (const float*)d_in[8];
    float* out = (float*)d_out;

    unsigned short* Xb   = (unsigned short*)((char*)d_ws + XB_OFF);
    unsigned short* h_ex = (unsigned short*)((char*)d_ws + HEX_OFF);
    unsigned*       ctr  = (unsigned*)((char*)d_ws + CTR_OFF);

    // zero h_ex (h_{-1}=0) + barrier counters
    hipMemsetAsync((char*)d_ws + HEX_OFF, 0, (128ull + 64ull) << 10, stream);
    k_xpose<<<8192, 256, 0, stream>>>(X, Xb);
    k_bilstm<<<64, 256, 0, stream>>>(Wih_f, Whh_f, bih_f, bhh_f,
                                     Wih_b, Whh_b, bih_b, bhh_b,
                                     Xb, h_ex, ctr, out);
}

// Round 3
// 3656.303 us; speedup vs baseline: 1.1908x; 1.1661x over previous
//
#include <hip/hip_runtime.h>
#include <hip/hip_bf16.h>

// Problem dims
#define BSZ 32
#define SSZ 512
#define ISZ 512
#define HSZ 512
#define PW  32          // workgroups per direction
// ws layout (bytes)
#define XB_OFF   0ull                       // [S][64 kc][32 b][8] ushort (bf16 bits) = 16 MB
#define HEX_OFF  (16ull << 20)              // [2 dir][2 buf][64 kc][32 b][8] ushort = 128 KB
#define CTR_OFF  (HEX_OFF + (128ull << 10)) // flags: [dir] stride 2048 dwords; 32 used per dir

typedef __attribute__((ext_vector_type(8)))  short short8;
typedef __attribute__((ext_vector_type(4)))  float f32x4;
typedef __attribute__((ext_vector_type(4)))  unsigned short us4;

__device__ __forceinline__ unsigned short f2bf(float f) {
    union { float f; unsigned u; } v; v.f = f;
    unsigned r = v.u + 0x7fffu + ((v.u >> 16) & 1u);   // RNE
    return (unsigned short)(r >> 16);
}

__device__ __forceinline__ float sigf(float x) { return 1.0f / (1.0f + __expf(-x)); }
__device__ __forceinline__ float tanhfast(float x) {
    float a = fabsf(x);
    float e = __expf(-2.0f * a);
    float t = (1.0f - e) / (1.0f + e);
    return x < 0.0f ? -t : t;
}

// X [B][S][I] fp32 -> Xb [t][kc][b][8] bf16-bits (MFMA A-fragment friendly layout)
__global__ void k_xpose(const float* __restrict__ X, unsigned short* __restrict__ Xb) {
    int idx = blockIdx.x * 256 + threadIdx.x;     // 2^21 threads total
    int i4 = idx & 127;                           // float4 index along I
    int t  = (idx >> 7) & 511;
    int b  = idx >> 16;
    float4 v = reinterpret_cast<const float4*>(X)[idx];
    us4 o = { f2bf(v.x), f2bf(v.y), f2bf(v.z), f2bf(v.w) };
    *reinterpret_cast<us4*>(Xb + (size_t)t * 16384 + (size_t)(i4 >> 1) * 256 + b * 8 + (i4 & 1) * 4) = o;
}

__launch_bounds__(256, 1)
__global__ void k_bilstm(const float* __restrict__ Wih_f, const float* __restrict__ Whh_f,
                         const float* __restrict__ bih_f, const float* __restrict__ bhh_f,
                         const float* __restrict__ Wih_b, const float* __restrict__ Whh_b,
                         const float* __restrict__ bih_b, const float* __restrict__ bhh_b,
                         const unsigned short* __restrict__ Xb,
                         unsigned short* h_ex, unsigned* flags, float* __restrict__ out)
{
    const int tid = threadIdx.x;
    const int dir = blockIdx.x & 1;     // 0 = fwd, 1 = bwd
    const int p   = blockIdx.x >> 1;    // 0..31 : owns h-cols [16p, 16p+16)
    const int wv  = tid >> 6;
    const int ln  = tid & 63;
    const int kh  = wv >> 1;            // 0: x-projection, 1: h-recurrence
    const int nt  = wv & 1;             // gate-pair tile (0: i,f ; 1: g,o)
    const int q   = ln >> 4;            // quad within wave
    const int m15 = ln & 15;

    const float* Wsel = kh ? (dir ? Whh_b : Whh_f) : (dir ? Wih_b : Wih_f);
    const float* bi   = dir ? bih_b : bih_f;
    const float* bh   = dir ? bhh_b : bhh_f;

    __shared__ float gates[2][32][67];   // 67: breaks even-bank 4-way conflicts
    __shared__ float cst[32][16];
    __shared__ float bias[64];

    // ---- load B fragments (weights) into registers, kept for all 512 steps ----
    short8 breg[16][2];
    {
        const float* wr0 = Wsel + (size_t)((nt * 2 + 0) * 512 + p * 16 + m15) * 512 + q * 8;
        const float* wr1 = Wsel + (size_t)((nt * 2 + 1) * 512 + p * 16 + m15) * 512 + q * 8;
#pragma unroll
        for (int ks = 0; ks < 16; ++ks) {
            short8 b0, b1;
#pragma unroll
            for (int j = 0; j < 8; ++j) {
                b0[j] = (short)f2bf(wr0[ks * 32 + j]);
                b1[j] = (short)f2bf(wr1[ks * 32 + j]);
            }
            breg[ks][0] = b0; breg[ks][1] = b1;
        }
    }

    if (tid < 64) {
        int c = tid;
        int gr = (c >> 4) * 512 + p * 16 + (c & 15);
        bias[c] = bi[gr] + bh[gr];
    }
    for (int i = tid; i < 512; i += 256) ((float*)cst)[i] = 0.0f;
    __syncthreads();

    unsigned* flg = flags + (size_t)dir * 2048;      // 32 dwords = 1 cache line per dir
    unsigned short* hexd = h_ex + (size_t)dir * 2 * 16384;

    for (int s = 0; s < 512; ++s) {
        const int t = dir ? (511 - s) : s;

        // ---- GEMM: [32 x 512] @ [512 x 32cols] for this wave's K-half ----
        f32x4 acc00 = {0.f,0.f,0.f,0.f}, acc01 = {0.f,0.f,0.f,0.f};
        f32x4 acc10 = {0.f,0.f,0.f,0.f}, acc11 = {0.f,0.f,0.f,0.f};

        if (kh == 0) {
            // x-projection: no waiting ever; plain (L2-cacheable) loads
            const unsigned short* abase = Xb + (size_t)t * 16384;
#pragma unroll
            for (int ks = 0; ks < 16; ++ks) {
                const unsigned short* ap = abase + (size_t)(ks * 4 + q) * 256 + m15 * 8;
                short8 a0 = *reinterpret_cast<const short8*>(ap);
                short8 a1 = *reinterpret_cast<const short8*>(ap + 128);
                acc00 = __builtin_amdgcn_mfma_f32_16x16x32_bf16(a0, breg[ks][0], acc00, 0, 0, 0);
                acc01 = __builtin_amdgcn_mfma_f32_16x16x32_bf16(a0, breg[ks][1], acc01, 0, 0, 0);
                acc10 = __builtin_amdgcn_mfma_f32_16x16x32_bf16(a1, breg[ks][0], acc10, 0, 0, 0);
                acc11 = __builtin_amdgcn_mfma_f32_16x16x32_bf16(a1, breg[ks][1], acc11, 0, 0, 0);
            }
        } else {
            // h-recurrence: wait until ALL 32 producer flags reach s.
            // Read-only coalesced poll of one 128B line: lane ln&31 watches flag[p].
            if (s > 0) {
                const unsigned* fp = flg + (ln & 31);
                for (;;) {
                    unsigned v = __hip_atomic_load(fp, __ATOMIC_RELAXED, __HIP_MEMORY_SCOPE_AGENT);
                    if (__ballot((int)(v >= (unsigned)s)) == ~0ull) break;
                }
                asm volatile("" ::: "memory");
            }
            const unsigned* abase = reinterpret_cast<const unsigned*>(hexd + (size_t)((s + 1) & 1) * 16384);
#pragma unroll
            for (int ks = 0; ks < 16; ++ks) {
                const unsigned* ap = abase + ((ks * 4 + q) * 256 + m15 * 8) / 2;
                union { short8 s8; unsigned u[4]; } ua0, ua1;
#pragma unroll
                for (int w = 0; w < 4; ++w) {
                    ua0.u[w] = __hip_atomic_load(ap + w,      __ATOMIC_RELAXED, __HIP_MEMORY_SCOPE_AGENT);
                    ua1.u[w] = __hip_atomic_load(ap + 64 + w, __ATOMIC_RELAXED, __HIP_MEMORY_SCOPE_AGENT);
                }
                acc00 = __builtin_amdgcn_mfma_f32_16x16x32_bf16(ua0.s8, breg[ks][0], acc00, 0, 0, 0);
                acc01 = __builtin_amdgcn_mfma_f32_16x16x32_bf16(ua0.s8, breg[ks][1], acc01, 0, 0, 0);
                acc10 = __builtin_amdgcn_mfma_f32_16x16x32_bf16(ua1.s8, breg[ks][0], acc10, 0, 0, 0);
                acc11 = __builtin_amdgcn_mfma_f32_16x16x32_bf16(ua1.s8, breg[ks][1], acc11, 0, 0, 0);
            }
        }

        // ---- dump partial gates to LDS (C/D layout: col = ln&15, row = q*4 + r) ----
        {
            int rb = q * 4;
            int cb = nt * 32 + m15;
#pragma unroll
            for (int r = 0; r < 4; ++r) {
                gates[kh][rb + r][cb]           = acc00[r];
                gates[kh][rb + r][cb + 16]      = acc01[r];
                gates[kh][16 + rb + r][cb]      = acc10[r];
                gates[kh][16 + rb + r][cb + 16] = acc11[r];
            }
        }
        __syncthreads();   // sync#1: both dumps visible

        // ---- gate math: each thread handles (b, j0) and (b, j0+1) ----
        int b  = tid >> 3;
        int j0 = (tid & 7) * 2;
        float hv01[2], cn01[2];
        {
#pragma unroll
            for (int u = 0; u < 2; ++u) {
                int j = j0 + u;
                float ig = gates[0][b][j]      + gates[1][b][j]      + bias[j];
                float fg = gates[0][b][16 + j] + gates[1][b][16 + j] + bias[16 + j];
                float gg = gates[0][b][32 + j] + gates[1][b][32 + j] + bias[32 + j];
                float og = gates[0][b][48 + j] + gates[1][b][48 + j] + bias[48 + j];
                float cn = sigf(fg) * cst[b][j] + sigf(ig) * tanhfast(gg);
                cst[b][j] = cn;
                float hv = sigf(og) * tanhfast(cn);
                hv01[u] = hv; cn01[u] = cn;
            }
            // packed 2xbf16 write-through (sc1) store of h for the next step
            int hc0 = p * 16 + j0;
            unsigned pk = (unsigned)f2bf(hv01[0]) | ((unsigned)f2bf(hv01[1]) << 16);
            unsigned* dst = reinterpret_cast<unsigned*>(
                hexd + (size_t)(s & 1) * 16384 + (size_t)(hc0 >> 3) * 256 + b * 8 + (hc0 & 7));
            __hip_atomic_store(dst, pk, __ATOMIC_RELAXED, __HIP_MEMORY_SCOPE_AGENT);
        }

        // ---- publish: drain hex stores, block barrier, single flag STORE (no RMW) ----
        asm volatile("s_waitcnt vmcnt(0)" ::: "memory");
        __syncthreads();   // sync#2: all waves' hex stores acked; gates safe to reuse
        if (tid == 0) {
            __hip_atomic_store(flg + p, (unsigned)(s + 1), __ATOMIC_RELAXED, __HIP_MEMORY_SCOPE_AGENT);
        }

        // ---- out stores AFTER publish (off the critical sync path) ----
#pragma unroll
        for (int u = 0; u < 2; ++u) {
            int hc = p * 16 + j0 + u;
            out[(size_t)b * (512 * 1024) + (size_t)t * 1024 + dir * 512 + hc] = hv01[u];
            if (s == 511) {
                out[16777216 + dir * 16384 + b * 512 + hc] = hv01[u];            // stacked_h
                out[16777216 + 32768 + dir * 16384 + b * 512 + hc] = cn01[u];    // stacked_c
            }
        }
    }
}

extern "C" void kernel_launch(void* const* d_in, const int* in_sizes, int n_in,
                              void* d_out, int out_size, void* d_ws, size_t ws_size,
                              hipStream_t stream) {
    const float* X     = (const float*)d_in[0];
    const float* Wih_f = (const float*)d_in[1];
    const float* Whh_f = (const float*)d_in[2];
    const float* bih_f = (const float*)d_in[3];
    const float* bhh_f = (const float*)d_in[4];
    const float* Wih_b = (const float*)d_in[5];
    const float* Whh_b = (const float*)d_in[6];
    const float* bih_b = (const float*)d_in[7];
    const float* bhh_b = (const float*)d_in[8];
    float* out = (float*)d_out;

    unsigned short* Xb   = (unsigned short*)((char*)d_ws + XB_OFF);
    unsigned short* h_ex = (unsigned short*)((char*)d_ws + HEX_OFF);
    unsigned*       flg  = (unsigned*)((char*)d_ws + CTR_OFF);

    // zero h_ex (h_{-1}=0) + flags
    hipMemsetAsync((char*)d_ws + HEX_OFF, 0, (128ull + 64ull) << 10, stream);
    k_xpose<<<8192, 256, 0, stream>>>(X, Xb);
    k_bilstm<<<64, 256, 0, stream>>>(Wih_f, Whh_f, bih_f, bhh_f,
                                     Wih_b, Whh_b, bih_b, bhh_b,
                                     Xb, h_ex, flg, out);
}